// Round 1
// baseline (351.814 us; speedup 1.0000x reference)
//
#include <hip/hip_runtime.h>

#define EPS 1e-8f

// heads: (B=8, H=16, S=4096, D=128) fp32.
// anchor = h 0; others = h 1..14 (h 15 unused). out = mean(1 - cos_sim).
// One wave = 2 (b,s) pairs: lanes 0-31 pair A, lanes 32-63 pair B.
// Each lane holds float4 (4 of the 128 dims); row = 32 lanes * 16B = 512B coalesced.
__global__ __launch_bounds__(256) void SCL_75419625717886_kernel(
    const float* __restrict__ heads, float* __restrict__ out) {
    const int tid  = threadIdx.x;
    const int wave = tid >> 6;
    const int lane = tid & 63;
    const int half = (lane >> 5) & 1;
    const int sub  = lane & 31;

    // pair index over (b, s): 8 * 4096 = 32768 total; 8 pairs per block
    const int p = blockIdx.x * 8 + wave * 2 + half;
    const int b = p >> 12;   // / 4096
    const int s = p & 4095;  // % 4096

    const size_t hstride = (size_t)4096 * 128;
    const size_t rowbase = (((size_t)b * 16) * 4096 + (size_t)s) * 128 + (size_t)sub * 4;

    // anchor row (h = 0), kept in registers
    const float4 a = *(const float4*)(heads + rowbase);
    float n2a = a.x * a.x + a.y * a.y + a.z * a.z + a.w * a.w;
#pragma unroll
    for (int m = 1; m <= 16; m <<= 1) n2a += __shfl_xor(n2a, m, 64);

    float acc = 0.0f;
#pragma unroll
    for (int h = 1; h <= 14; ++h) {
        const float4 o = *(const float4*)(heads + rowbase + (size_t)h * hstride);
        float dp  = a.x * o.x + a.y * o.y + a.z * o.z + a.w * o.w;
        float n2o = o.x * o.x + o.y * o.y + o.z * o.z + o.w * o.w;
#pragma unroll
        for (int m = 1; m <= 16; m <<= 1) {
            dp  += __shfl_xor(dp,  m, 64);
            n2o += __shfl_xor(n2o, m, 64);
        }
        const float sim = dp / fmaxf(sqrtf(n2o * n2a), EPS);
        acc += 1.0f - sim;
    }

    // all 32 lanes of a half hold identical acc; xor-32 gives the wave total on every lane
    acc += __shfl_xor(acc, 32, 64);

    __shared__ float wsum[4];
    if (lane == 0) wsum[wave] = acc;
    __syncthreads();
    if (tid == 0) {
        const float scale = 1.0f / (8.0f * 14.0f * 4096.0f);
        atomicAdd(out, (wsum[0] + wsum[1] + wsum[2] + wsum[3]) * scale);
    }
}

extern "C" void kernel_launch(void* const* d_in, const int* in_sizes, int n_in,
                              void* d_out, int out_size, void* d_ws, size_t ws_size,
                              hipStream_t stream) {
    const float* heads = (const float*)d_in[0];
    float* out = (float*)d_out;
    // d_out is re-poisoned to 0xAA before every timed call — must zero it ourselves
    hipMemsetAsync(out, 0, sizeof(float), stream);
    dim3 grid(4096), block(256);
    hipLaunchKernelGGL(SCL_75419625717886_kernel, grid, block, 0, stream, heads, out);
}

// Round 2
// 346.852 us; speedup vs baseline: 1.0143x; 1.0143x over previous
//
#include <hip/hip_runtime.h>

#define EPS2 1e-16f

// heads: (B=8, H=16, S=4096, D=128) fp32.
// anchor = h 0; others = h 1..14 (h 15 unused). out = mean(1 - cos_sim).
//
// One wave = 8 (b,s) pairs: group g = lane>>3 (8 lanes/group) owns pair p.
// Each lane covers 16 of the 128 dims as 4x float4; load j has the group's
// 8 lanes reading 128 B contiguous (floats [32j, 32j+32) of the row).
// Reduction over a row = 3-step shuffle (xor 1,2,4) instead of 5-step.
__global__ __launch_bounds__(256) void SCL_75419625717886_kernel(
    const float* __restrict__ heads, float* __restrict__ out) {
    const int tid   = threadIdx.x;
    const int wave  = tid >> 6;
    const int lane  = tid & 63;
    const int group = lane >> 3;   // 0..7  (pair within wave)
    const int gl    = lane & 7;    // 0..7  (lane within group)

    // pair index over (b, s): 8 * 4096 = 32768 total; 32 pairs per block
    const int p = (blockIdx.x * 4 + wave) * 8 + group;
    const int b = p >> 12;   // / 4096
    const int s = p & 4095;  // % 4096

    const size_t hstride = (size_t)4096 * 128;
    // lane's 4 chunks: float4 at rowbase + 32*j + 4*gl, j=0..3
    const size_t rowbase = (((size_t)b * 16) * 4096 + (size_t)s) * 128 + (size_t)gl * 4;

    // ---- anchor row (h = 0), kept in registers ----
    float4 a0 = *(const float4*)(heads + rowbase);
    float4 a1 = *(const float4*)(heads + rowbase + 32);
    float4 a2 = *(const float4*)(heads + rowbase + 64);
    float4 a3 = *(const float4*)(heads + rowbase + 96);

    float n2a = a0.x*a0.x + a0.y*a0.y + a0.z*a0.z + a0.w*a0.w
              + a1.x*a1.x + a1.y*a1.y + a1.z*a1.z + a1.w*a1.w
              + a2.x*a2.x + a2.y*a2.y + a2.z*a2.z + a2.w*a2.w
              + a3.x*a3.x + a3.y*a3.y + a3.z*a3.z + a3.w*a3.w;
    n2a += __shfl_xor(n2a, 1, 64);
    n2a += __shfl_xor(n2a, 2, 64);
    n2a += __shfl_xor(n2a, 4, 64);

    float acc = 0.0f;
#pragma unroll
    for (int h = 1; h <= 14; ++h) {
        const float* r = heads + rowbase + (size_t)h * hstride;
        const float4 o0 = *(const float4*)(r);
        const float4 o1 = *(const float4*)(r + 32);
        const float4 o2 = *(const float4*)(r + 64);
        const float4 o3 = *(const float4*)(r + 96);

        float dp  = a0.x*o0.x + a0.y*o0.y + a0.z*o0.z + a0.w*o0.w
                  + a1.x*o1.x + a1.y*o1.y + a1.z*o1.z + a1.w*o1.w
                  + a2.x*o2.x + a2.y*o2.y + a2.z*o2.z + a2.w*o2.w
                  + a3.x*o3.x + a3.y*o3.y + a3.z*o3.z + a3.w*o3.w;
        float n2o = o0.x*o0.x + o0.y*o0.y + o0.z*o0.z + o0.w*o0.w
                  + o1.x*o1.x + o1.y*o1.y + o1.z*o1.z + o1.w*o1.w
                  + o2.x*o2.x + o2.y*o2.y + o2.z*o2.z + o2.w*o2.w
                  + o3.x*o3.x + o3.y*o3.y + o3.z*o3.z + o3.w*o3.w;

        dp  += __shfl_xor(dp,  1, 64);  n2o += __shfl_xor(n2o, 1, 64);
        dp  += __shfl_xor(dp,  2, 64);  n2o += __shfl_xor(n2o, 2, 64);
        dp  += __shfl_xor(dp,  4, 64);  n2o += __shfl_xor(n2o, 4, 64);

        // sim = dp / max(sqrt(n2o*n2a), 1e-8); norms ~11 so eps guard is inert
        const float sim = dp * __builtin_amdgcn_rsqf(fmaxf(n2o * n2a, EPS2));
        acc += 1.0f - sim;
    }

    // acc is uniform within each 8-lane group; xor 8,16,32 sums the 8 groups
    acc += __shfl_xor(acc,  8, 64);
    acc += __shfl_xor(acc, 16, 64);
    acc += __shfl_xor(acc, 32, 64);

    __shared__ float wsum[4];
    if (lane == 0) wsum[wave] = acc;
    __syncthreads();
    if (tid == 0) {
        const float scale = 1.0f / (8.0f * 14.0f * 4096.0f);
        atomicAdd(out, (wsum[0] + wsum[1] + wsum[2] + wsum[3]) * scale);
    }
}

extern "C" void kernel_launch(void* const* d_in, const int* in_sizes, int n_in,
                              void* d_out, int out_size, void* d_ws, size_t ws_size,
                              hipStream_t stream) {
    const float* heads = (const float*)d_in[0];
    float* out = (float*)d_out;
    // d_out is re-poisoned to 0xAA before every timed call — must zero it ourselves
    hipMemsetAsync(out, 0, sizeof(float), stream);
    dim3 grid(1024), block(256);
    hipLaunchKernelGGL(SCL_75419625717886_kernel, grid, block, 0, stream, heads, out);
}